// Round 6
// baseline (2700.180 us; speedup 1.0000x reference)
//
#include <hip/hip_runtime.h>
#include <hip/hip_fp16.h>

#define NB 256
#define NT 512

// ---------------- workspace layout (bytes) ----------------
// 0        barrier region (4096)       -- memset 0 each launch (4 tree barriers)
// 4096     eDat  u64[2][2048]  32768   -- packed {hf,hr}, 2-bit mod-4 tag in each word
// 36864    hDec  f32[2][2][1024] 16384 -- decoder h, 2-bit mod-4 tag per word
// 69632    common f32[512]      2048
// 71680    bsum  f32[2][4096]  32768
// 104448   d1    f32[2][4096]  32768
// 137216   embf  f32[256][1024] 1048576
// 1204224  P     f32[2][8192][256] 16777216
// 17981440 Wcomb fp16[2][4096][1024] 16777216
// 34758656 WhhE  fp16[8192][2048] 33554432
// total fast: 68313088
//
// R12 = R11 protocol (lockstep 2-barrier, all-or-retry, fire-and-forget)
// + 3 serial-path micro-deltas:
// (a) 2-bit mod-4 tag in the 2 mantissa LSBs of EVERY 4B word (err 4e-7):
//     every word self-validates -> tear-proof at any load width. Poll t sees
//     only {t, t-2, init}; t vs t-2 always differ mod 4; init pattern ==3
//     aliases only polls whose buffer the induction proves overwritten.
// (b) wide polls: encoder 2x global_load_dwordx4 sc1 (4 slots, one wait);
//     decoder h slot = 4B -> ONE 8B load; staging via ds_write_b128/b64
//     (thread owns slots 4t..4t+3 / 2t..2t+1).
// (c) decoder outrec (HBM) store deferred past next poll-detect: removes
//     HBM-store completion from the poll's vmcnt(0) drain.

typedef unsigned u32x4 __attribute__((ext_vector_type(4)));

struct KArgs {
  const int *x, *Vg, *Jg;
  const float *emb, *embVg, *embJg;
  const float *encWih, *encWhh, *encBih, *encBhh;
  const float *clsW, *clsB, *latfW, *latfB, *latrW, *latrB, *mixW, *mixB;
  const float *recWih[2], *recWhh[2], *recBih[2], *recBhh[2];
  float* out;
  unsigned* barFull;
  unsigned long long* eDat;
  float *hDec, *common, *bsum, *d1, *embf, *P;
  unsigned short *Wcomb, *WhhE;
  int fast;
};

__device__ __forceinline__ unsigned packh2(float lo, float hi) {
  __half2 h = __floats2half2_rn(lo, hi);
  return *(unsigned*)&h;
}
__device__ __forceinline__ float2 h2f2(unsigned u) {
  __half2 h = *(__half2*)&u;
  return __half22float2(h);
}
__device__ __forceinline__ float sigm(float x) { return 1.f / (1.f + __expf(-x)); }
__device__ __forceinline__ float tanh_(float x) { return 2.f / (1.f + __expf(-2.f * x)) - 1.f; }
__device__ __forceinline__ float wred(float v) {
#pragma unroll
  for (int off = 32; off; off >>= 1) v += __shfl_xor(v, off, 64);
  return v;
}
// agent-scope (device-coherent) accesses: bypass non-coherent per-XCD L2.
__device__ __forceinline__ void cstoref(float* p, float v) {
  __hip_atomic_store(p, v, __ATOMIC_RELAXED, __HIP_MEMORY_SCOPE_AGENT);
}
__device__ __forceinline__ float cloadf(const float* p) {
  return __hip_atomic_load(p, __ATOMIC_RELAXED, __HIP_MEMORY_SCOPE_AGENT);
}
__device__ __forceinline__ void cstoreu(unsigned* p, unsigned v) {
  __hip_atomic_store(p, v, __ATOMIC_RELAXED, __HIP_MEMORY_SCOPE_AGENT);
}
__device__ __forceinline__ unsigned long long cload64(const unsigned long long* p) {
  return __hip_atomic_load(p, __ATOMIC_RELAXED, __HIP_MEMORY_SCOPE_AGENT);
}
__device__ __forceinline__ void cstore64(unsigned long long* p, unsigned long long v) {
  __hip_atomic_store(p, v, __ATOMIC_RELAXED, __HIP_MEMORY_SCOPE_AGENT);
}
// 32B device-scope poll load: two dwordx4 in flight, ONE wait (keeps the
// round at a single L3 latency). sc1 = device scope (matches the agent-scope
// builtins' cache behavior: bypass L1/L2 to the coherence point).
__device__ __forceinline__ void cload32B(const void* p, u32x4& A, u32x4& B) {
  asm volatile(
      "global_load_dwordx4 %0, %2, off sc1\n\t"
      "global_load_dwordx4 %1, %2, off offset:16 sc1\n\t"
      "s_waitcnt vmcnt(0)"
      : "=&v"(A), "=&v"(B)
      : "v"(p)
      : "memory");
}

// Tree barrier (4 uses). acq-rel RMWs + acquire fence order pre-barrier
// setup stores before post-barrier consumers.
__device__ __forceinline__ void gbar_tree(unsigned* tree, int idx, unsigned e) {
  const int ls = 8;
  __syncthreads();
  if (threadIdx.x == 0) {
    unsigned* leaf = tree + (idx >> 3) * ls;
    unsigned* root = tree + 32 * ls;
    unsigned* flag = root + ls;
    unsigned old = __hip_atomic_fetch_add(leaf, 1u, __ATOMIC_ACQ_REL, __HIP_MEMORY_SCOPE_AGENT);
    if (old == e * 8u - 1u) {
      unsigned ro = __hip_atomic_fetch_add(root, 1u, __ATOMIC_ACQ_REL, __HIP_MEMORY_SCOPE_AGENT);
      if (ro == e * 32u - 1u)
        __hip_atomic_store(flag, e, __ATOMIC_RELEASE, __HIP_MEMORY_SCOPE_AGENT);
    }
    while (__hip_atomic_load(flag, __ATOMIC_RELAXED, __HIP_MEMORY_SCOPE_AGENT) < e)
      __builtin_amdgcn_s_sleep(2);
    __builtin_amdgcn_fence(__ATOMIC_ACQUIRE, "agent");
  }
  __syncthreads();
}

__global__ __launch_bounds__(NT, 2) void rnn2_kernel(KArgs a) {
  __shared__ float smem[16384];  // 64 KB, reused per phase
  const int tid = threadIdx.x;
  const int b = blockIdx.x;
  const int wq = __builtin_amdgcn_readfirstlane(tid >> 6);
  const int lane = tid & 63;

  float* out_recf = a.out + 1280;
  float* out_recr = a.out + 1280 + 262144;
  float* out_embf = a.out + 1280 + 2 * 262144;
  float* out_embr = a.out + 1280 + 3 * 262144;

  // ================= phase 0a =================
  for (int i = tid; i < 2048; i += NT) smem[i] = a.emb[i];
  __syncthreads();
  {  // d1[dir][row] = start_vec @ Wih.T + bih + bhh   (dir0: emb[0], dir1: emb[1])
    int wg = b * 8 + wq;
#pragma unroll 1
    for (int rr = 0; rr < 4; rr++) {
      int idx = wg + rr * 2048;
      int dir = idx >> 12;
      int row = idx & 4095;
      const float* Wih = a.recWih[dir];
      const float* sv = &smem[dir * 1024];
      float acc = 0.f;
#pragma unroll
      for (int kc = 0; kc < 4; kc++) {
        int k = kc * 256 + lane * 4;
        float4 wv = *(const float4*)&Wih[row * 1024 + k];
        float4 ev = *(const float4*)&sv[k];
        acc += wv.x * ev.x + wv.y * ev.y + wv.z * ev.z + wv.w * ev.w;
      }
      acc = wred(acc);
      if (lane == 0)
        cstoref(&a.d1[dir * 4096 + row], acc + a.recBih[dir][row] + a.recBhh[dir][row]);
    }
  }
  const int gtid = b * NT + tid;
  const int GSZ = NB * NT;
  for (int i = gtid; i < 256 * 1024; i += GSZ) {
    int t = i >> 10, e = i & 1023;
    float v = a.emb[a.x[t] * 1024 + e];
    cstoref(&a.embf[i], v);
    out_embf[i] = v;
    out_embr[(255 - t) * 1024 + e] = v;
  }
  if (gtid < 1024) {
    int e = gtid;
    out_recf[e] = a.emb[1024 + e];
    out_recf[255 * 1024 + e] = a.emb[e];
    out_recr[e] = a.emb[e];
    out_recr[255 * 1024 + e] = a.emb[1024 + e];
  }
  // exchange-buffer init: every 4B word pattern ==3 (mod 4). Aliases only
  // tag==3 polls, whose buffer the induction proves overwritten by then.
  if (gtid < 4096) cstore64(&a.eDat[gtid], 0x0000000300000003ULL);
  if (gtid < 4096) cstoreu((unsigned*)a.hDec + gtid, 3u);
  if (gtid < 8192) {
    int dir = gtid >> 12, r = gtid & 4095;
    cstoref(&a.bsum[gtid], a.recBih[dir][r] + a.recBhh[dir][r]);
  }
  if (a.fast) {
    unsigned* W32 = (unsigned*)a.WhhE;
    const int N4 = 8192 * 2048 / 4;
    for (int i = gtid; i < N4; i += GSZ) {
      float4 v = *(const float4*)&a.encWhh[(size_t)i * 4];
      cstoreu(&W32[i * 2], packh2(v.x, v.y));
      cstoreu(&W32[i * 2 + 1], packh2(v.z, v.w));
    }
    unsigned* C32 = (unsigned*)a.Wcomb;
    const int M4 = 4096 * 1024 / 4;
    for (int i = gtid; i < 2 * M4; i += GSZ) {
      int dir = (i >= M4) ? 1 : 0;
      int j = i - dir * M4;
      float4 va = *(const float4*)&a.recWih[dir][(size_t)j * 4];
      float4 vb = *(const float4*)&a.recWhh[dir][(size_t)j * 4];
      cstoreu(&C32[(size_t)dir * (M4 * 2) + j * 2], packh2(va.x + vb.x, va.y + vb.y));
      cstoreu(&C32[(size_t)dir * (M4 * 2) + j * 2 + 1], packh2(va.z + vb.z, va.w + vb.w));
    }
  }
  gbar_tree(a.barFull, b, 1u);

  // ================= phase 0b: P GEMM =================
  {
    const int tdb = b & 7;
    const int rb = (b >> 3) * 256;
    const int td = tdb * 64 + lane;
    const int dirc = td >> 8;
    const int tcol = td & 255;
    float acc[2][16];
#pragma unroll
    for (int p = 0; p < 2; p++)
#pragma unroll
      for (int r = 0; r < 16; r++) acc[p][r] = 0.f;
    const int s_td = tid >> 3;
    const int s_j = tid & 7;
    int std_ = tdb * 64 + s_td;
    int st = std_ & 255;
    const float* s_esrc = &a.embf[((std_ >> 8) ? (255 - st) : st) * 1024];
#pragma unroll 1
    for (int kc = 0; kc < 4; kc++) {
      __syncthreads();
#pragma unroll
      for (int m = 0; m < 8; m++) {
        int kk = s_j * 32 + m * 4;
        float4 v = *(const float4*)&s_esrc[kc * 256 + kk];
        smem[(kk + 0) * 64 + s_td] = v.x;
        smem[(kk + 1) * 64 + s_td] = v.y;
        smem[(kk + 2) * 64 + s_td] = v.z;
        smem[(kk + 3) * 64 + s_td] = v.w;
      }
      __syncthreads();
#pragma unroll
      for (int p = 0; p < 2; p++) {
        int row0 = rb + wq * 32 + p * 16;
#pragma unroll 1
        for (int k4 = 0; k4 < 64; k4++) {
          float e0 = smem[(k4 * 4 + 0) * 64 + lane];
          float e1 = smem[(k4 * 4 + 1) * 64 + lane];
          float e2 = smem[(k4 * 4 + 2) * 64 + lane];
          float e3 = smem[(k4 * 4 + 3) * 64 + lane];
#pragma unroll
          for (int r = 0; r < 16; r++) {
            const float* wp = &a.encWih[(size_t)(row0 + r) * 1024 + kc * 256 + k4 * 4];
            float w0 = wp[0], w1 = wp[1], w2 = wp[2], w3 = wp[3];
            acc[p][r] = fmaf(e0, w0, fmaf(e1, w1, fmaf(e2, w2, fmaf(e3, w3, acc[p][r]))));
          }
        }
      }
    }
#pragma unroll
    for (int p = 0; p < 2; p++)
#pragma unroll
      for (int r = 0; r < 16; r++) {
        int row = rb + wq * 32 + p * 16 + r;
        float bias = a.encBih[row] + a.encBhh[row];
        cstoref(&a.P[(size_t)(dirc * 8192 + row) * 256 + tcol], acc[p][r] + bias);
      }
  }
  gbar_tree(a.barFull, b, 2u);

  // ===== encoder: 256 steps, lockstep, wide-poll tagged exchange =====
  {
    const int u = b * 8 + wq;
    float wreg[128];  // VGPR-resident Whh slice: 4 gates x 2048 k (32 k/lane)
    if (a.fast) {
      const unsigned long long* W64 = (const unsigned long long*)a.WhhE;
#pragma unroll
      for (int g = 0; g < 4; g++)
#pragma unroll
        for (int c = 0; c < 8; c++) {
          unsigned long long w = cload64(&W64[(size_t)(g * 2048 + u) * 512 + c * 64 + lane]);
          float2 f01 = h2f2((unsigned)w), f23 = h2f2((unsigned)(w >> 32));
          wreg[(g * 8 + c) * 4 + 0] = f01.x;
          wreg[(g * 8 + c) * 4 + 1] = f01.y;
          wreg[(g * 8 + c) * 4 + 2] = f23.x;
          wreg[(g * 8 + c) * 4 + 3] = f23.y;
        }
    }
    float cf = 0.f, cr = 0.f;
#pragma unroll 1
    for (int t = 0; t < 256; t++) {
      float pf[4], pr[4];  // agent loads, issued early: hide behind the poll
#pragma unroll
      for (int g = 0; g < 4; g++) {
        pf[g] = cloadf(&a.P[(size_t)(g * 2048 + u) * 256 + t]);
        pr[g] = cloadf(&a.P[(size_t)(8192 + g * 2048 + u) * 256 + t]);
      }
      if (t == 0) {
#pragma unroll
        for (int j = 0; j < 8; j++) smem[j * 512 + tid] = 0.f;  // h0 = 0
      } else {
        // all-or-retry poll: thread owns slots 4t..4t+3 (32B) via 2x dwordx4
        // (one wait). Every 4B word self-validates with tag t&3.
        const char* dp = (const char*)(a.eDat + (size_t)(t & 1) * 2048) + 32 * tid;
        const unsigned tg2 = (unsigned)t & 3u;
        u32x4 A, B;
        for (;;) {
          cload32B(dp, A, B);
          unsigned bad = (A.x ^ tg2) | (A.y ^ tg2) | (A.z ^ tg2) | (A.w ^ tg2) |
                         (B.x ^ tg2) | (B.y ^ tg2) | (B.z ^ tg2) | (B.w ^ tg2);
          if (!(bad & 3u)) break;
          __builtin_amdgcn_s_sleep(1);
        }
        float4 sf, sr;  // slot i = {hf_i (lo), hr_i (hi)}
        sf.x = __uint_as_float(A.x); sr.x = __uint_as_float(A.y);
        sf.y = __uint_as_float(A.z); sr.y = __uint_as_float(A.w);
        sf.z = __uint_as_float(B.x); sr.z = __uint_as_float(B.y);
        sf.w = __uint_as_float(B.z); sr.w = __uint_as_float(B.w);
        *(float4*)&smem[4 * tid] = sf;
        *(float4*)&smem[2048 + 4 * tid] = sr;
      }
      __syncthreads();
      float af[4] = {0, 0, 0, 0}, ar[4] = {0, 0, 0, 0};
      if (a.fast) {
#pragma unroll
        for (int c = 0; c < 8; c++) {
          float4 hf = *(const float4*)&smem[c * 256 + lane * 4];
          float4 hr = *(const float4*)&smem[2048 + c * 256 + lane * 4];
#pragma unroll
          for (int g = 0; g < 4; g++) {
            const int wb = (g * 8 + c) * 4;
            af[g] = fmaf(wreg[wb + 0], hf.x, fmaf(wreg[wb + 1], hf.y,
                    fmaf(wreg[wb + 2], hf.z, fmaf(wreg[wb + 3], hf.w, af[g]))));
            ar[g] = fmaf(wreg[wb + 0], hr.x, fmaf(wreg[wb + 1], hr.y,
                    fmaf(wreg[wb + 2], hr.z, fmaf(wreg[wb + 3], hr.w, ar[g]))));
          }
        }
      } else {
#pragma unroll 1
        for (int kc = 0; kc < 8; kc++) {
          int k = kc * 256 + lane * 4;
          float4 hf = *(const float4*)&smem[k];
          float4 hr = *(const float4*)&smem[2048 + k];
#pragma unroll
          for (int g = 0; g < 4; g++) {
            float4 wv = *(const float4*)&a.encWhh[(size_t)(g * 2048 + u) * 2048 + k];
            af[g] += wv.x * hf.x + wv.y * hf.y + wv.z * hf.z + wv.w * hf.w;
            ar[g] += wv.x * hr.x + wv.y * hr.y + wv.z * hr.z + wv.w * hr.w;
          }
        }
      }
#pragma unroll
      for (int g = 0; g < 4; g++) { af[g] = wred(af[g]); ar[g] = wred(ar[g]); }
      float gi = af[0] + pf[0], gf = af[1] + pf[1], gg = af[2] + pf[2], go = af[3] + pf[3];
      cf = sigm(gf) * cf + sigm(gi) * tanh_(gg);
      float hfv = sigm(go) * tanh_(cf);
      gi = ar[0] + pr[0]; gf = ar[1] + pr[1]; gg = ar[2] + pr[2]; go = ar[3] + pr[3];
      cr = sigm(gf) * cr + sigm(gi) * tanh_(gg);
      float hrv = sigm(go) * tanh_(cr);
      if (lane == 0) {  // fire-and-forget: both words tagged (t+1)&3
        unsigned tag = (unsigned)(t + 1) & 3u;
        unsigned fa = (__float_as_uint(hfv) & ~3u) | tag;
        unsigned fb = (__float_as_uint(hrv) & ~3u) | tag;
        cstore64(&a.eDat[(size_t)((t + 1) & 1) * 2048 + u],
                 ((unsigned long long)fb << 32) | fa);
      }
      __syncthreads();  // lockstep: protect smem before next staging
    }
  }

  // ================= latents: tree-barrier sequenced =================
  if (b <= 192) {
    {  // final h: eDat buf 0, tag 256 -> mod4 == 0; wide all-or-retry
      const char* dp = (const char*)a.eDat + 32 * tid;
      u32x4 A, B;
      for (;;) {
        cload32B(dp, A, B);
        unsigned bad = A.x | A.y | A.z | A.w | B.x | B.y | B.z | B.w;
        if (!(bad & 3u)) break;
        __builtin_amdgcn_s_sleep(1);
      }
      float4 sf, sr;
      sf.x = __uint_as_float(A.x); sr.x = __uint_as_float(A.y);
      sf.y = __uint_as_float(A.z); sr.y = __uint_as_float(A.w);
      sf.z = __uint_as_float(B.x); sr.z = __uint_as_float(B.y);
      sf.w = __uint_as_float(B.z); sr.w = __uint_as_float(B.w);
      *(float4*)&smem[4 * tid] = sf;
      *(float4*)&smem[2048 + 4 * tid] = sr;
    }
    __syncthreads();
    int wg = b * 8 + wq;
    if (wg < 512) {  // common row
      int r = wg;
      float acc = 0.f;
#pragma unroll 1
      for (int kc = 0; kc < 16; kc++) {
        int k = kc * 256 + lane * 4;
        float4 wv = *(const float4*)&a.clsW[(size_t)r * 4096 + k];
        float4 hv = *(const float4*)&smem[k];
        acc += wv.x * hv.x + wv.y * hv.y + wv.z * hv.z + wv.w * hv.w;
      }
      acc = wred(acc);
      if (lane == 0) cstoref(&a.common[r], tanh_(acc + a.clsB[r]));
    } else if (wg < 1024) {  // lat_f
      int r = wg - 512;
      float acc = 0.f;
#pragma unroll 1
      for (int kc = 0; kc < 8; kc++) {
        int k = kc * 256 + lane * 4;
        float4 wv = *(const float4*)&a.latfW[(size_t)r * 2048 + k];
        float4 hv = *(const float4*)&smem[k];
        acc += wv.x * hv.x + wv.y * hv.y + wv.z * hv.z + wv.w * hv.w;
      }
      acc = wred(acc);
      if (lane == 0) {
        float v = acc + a.latfB[r];
        cstoref(&a.hDec[64 + r], __uint_as_float(__float_as_uint(v) & ~3u));  // tag 0
        a.out[64 + r] = v;
      }
    } else if (wg < 1536) {  // lat_r
      int r = wg - 1024;
      float acc = 0.f;
#pragma unroll 1
      for (int kc = 0; kc < 8; kc++) {
        int k = kc * 256 + lane * 4;
        float4 wv = *(const float4*)&a.latrW[(size_t)r * 2048 + k];
        float4 hv = *(const float4*)&smem[2048 + k];
        acc += wv.x * hv.x + wv.y * hv.y + wv.z * hv.z + wv.w * hv.w;
      }
      acc = wred(acc);
      if (lane == 0) {
        float v = acc + a.latrB[r];
        cstoref(&a.hDec[1024 + 64 + r], __uint_as_float(__float_as_uint(v) & ~3u));
        a.out[640 + 64 + r] = v;
      }
    } else if (wg == 1536) {  // vg
      float v = a.embVg[a.Vg[0] * 64 + lane];
      float tv = __uint_as_float(__float_as_uint(v) & ~3u);
      cstoref(&a.hDec[lane], tv);
      cstoref(&a.hDec[1024 + lane], tv);
      a.out[lane] = v;
      a.out[640 + lane] = v;
    } else if (wg == 1537) {  // jg
      float v = a.embJg[a.Jg[0] * 64 + lane];
      float tv = __uint_as_float(__float_as_uint(v) & ~3u);
      cstoref(&a.hDec[576 + lane], tv);
      cstoref(&a.hDec[1024 + 576 + lane], tv);
      a.out[576 + lane] = v;
      a.out[640 + 576 + lane] = v;
    }
  }
  gbar_tree(a.barFull, b, 3u);  // common + lat + vg/jg complete, grid-wide
  if (b < 48) {  // mix rows 0..383
    int wg = b * 8 + wq;
    smem[tid] = cloadf(&a.common[tid]);  // 512 threads, 512 entries
    __syncthreads();
    float acc = 0.f;
#pragma unroll
    for (int kc = 0; kc < 2; kc++) {
      int k = kc * 256 + lane * 4;
      float4 wv = *(const float4*)&a.mixW[(size_t)wg * 512 + k];
      float4 hv = *(const float4*)&smem[k];
      acc += wv.x * hv.x + wv.y * hv.y + wv.z * hv.z + wv.w * hv.w;
    }
    acc = wred(acc);
    if (lane == 0) {
      float v = acc + a.mixB[wg];
      float tv = __uint_as_float(__float_as_uint(v) & ~3u);
      cstoref(&a.hDec[640 + wg], tv);
      cstoref(&a.hDec[1024 + 640 + wg], tv);
    }
  }
  gbar_tree(a.barFull, b, 4u);  // full h0 (tag 0) in hDec buf0, grid-wide

  // ========== decoders: 254 steps, lockstep tagged exchange ==========
  {
    const int dir = b & 1;
    const int hidx = b >> 1;
    const int u = hidx * 8 + wq;
    float* outrec = dir ? out_recr : out_recf;
    float bs[4];
#pragma unroll
    for (int g = 0; g < 4; g++) bs[g] = cloadf(&a.bsum[dir * 4096 + g * 1024 + u]);
    float wd[64];  // VGPR-resident Wcomb slice: 4 gates x 1024 k (16 k/lane)
    if (a.fast) {
      const unsigned long long* C64 = (const unsigned long long*)a.Wcomb;
      const size_t dbase = (size_t)dir * (4096 * 1024 / 4);
#pragma unroll
      for (int g = 0; g < 4; g++)
#pragma unroll
        for (int c = 0; c < 4; c++) {
          unsigned long long w = cload64(&C64[dbase + (size_t)(g * 1024 + u) * 256 + c * 64 + lane]);
          float2 f01 = h2f2((unsigned)w), f23 = h2f2((unsigned)(w >> 32));
          wd[(g * 4 + c) * 4 + 0] = f01.x;
          wd[(g * 4 + c) * 4 + 1] = f01.y;
          wd[(g * 4 + c) * 4 + 2] = f23.x;
          wd[(g * 4 + c) * 4 + 3] = f23.y;
        }
    }
    float c = 0.f, h2p = 0.f;
#pragma unroll 1
    for (int s = 1; s <= 254; s++) {
      {  // all-or-retry poll: ONE 8B load = slots 2t,2t+1; tag (s-1)&3/word
        const unsigned long long* src =
            (const unsigned long long*)(a.hDec + ((s - 1) & 1) * 2048 + dir * 1024);
        const unsigned tg2 = (unsigned)(s - 1) & 3u;
        unsigned long long v;
        for (;;) {
          v = cload64(&src[tid]);
          unsigned bad = ((unsigned)v ^ tg2) | (((unsigned)(v >> 32)) ^ tg2);
          if (!(bad & 3u)) break;
          __builtin_amdgcn_s_sleep(1);
        }
        float2 sv;
        sv.x = __uint_as_float((unsigned)v);
        sv.y = __uint_as_float((unsigned)(v >> 32));
        *(float2*)&smem[2 * tid] = sv;
      }
      // deferred HBM output of previous step (off the poll's vmcnt path)
      if (lane == 0 && s > 1) outrec[(size_t)(255 - (s - 1)) * 1024 + u] = h2p;
      __syncthreads();
      float acc[4] = {0, 0, 0, 0};
      if (s == 1) {  // g = d1 + h0 @ Whh.T  (f32 weights, one step)
        const float* Whh = a.recWhh[dir];
#pragma unroll 1
        for (int kc = 0; kc < 4; kc++) {
          int k = kc * 256 + lane * 4;
          float4 hv = *(const float4*)&smem[k];
#pragma unroll
          for (int g = 0; g < 4; g++) {
            float4 wv = *(const float4*)&Whh[(size_t)(g * 1024 + u) * 1024 + k];
            acc[g] += wv.x * hv.x + wv.y * hv.y + wv.z * hv.z + wv.w * hv.w;
          }
        }
      } else if (a.fast) {
#pragma unroll
        for (int cc = 0; cc < 4; cc++) {
          float4 hv = *(const float4*)&smem[cc * 256 + lane * 4];
#pragma unroll
          for (int g = 0; g < 4; g++) {
            const int wb = (g * 4 + cc) * 4;
            acc[g] = fmaf(wd[wb + 0], hv.x, fmaf(wd[wb + 1], hv.y,
                     fmaf(wd[wb + 2], hv.z, fmaf(wd[wb + 3], hv.w, acc[g]))));
          }
        }
      } else {
        const float* Wi = a.recWih[dir];
        const float* Wh = a.recWhh[dir];
#pragma unroll 1
        for (int kc = 0; kc < 4; kc++) {
          int k = kc * 256 + lane * 4;
          float4 hv = *(const float4*)&smem[k];
#pragma unroll
          for (int g = 0; g < 4; g++) {
            size_t ro = (size_t)(g * 1024 + u) * 1024 + k;
            float4 va = *(const float4*)&Wi[ro];
            float4 vb = *(const float4*)&Wh[ro];
            acc[g] += (va.x + vb.x) * hv.x + (va.y + vb.y) * hv.y +
                      (va.z + vb.z) * hv.z + (va.w + vb.w) * hv.w;
          }
        }
      }
#pragma unroll
      for (int g = 0; g < 4; g++) acc[g] = wred(acc[g]);
      float gi, gf, gg, go;
      if (s == 1) {
        gi = acc[0] + cloadf(&a.d1[dir * 4096 + u]);
        gf = acc[1] + cloadf(&a.d1[dir * 4096 + 1024 + u]);
        gg = acc[2] + cloadf(&a.d1[dir * 4096 + 2048 + u]);
        go = acc[3] + cloadf(&a.d1[dir * 4096 + 3072 + u]);
        c = smem[u];  // c0 = h0
      } else {
        gi = acc[0] + bs[0]; gf = acc[1] + bs[1]; gg = acc[2] + bs[2]; go = acc[3] + bs[3];
      }
      c = sigm(gf) * c + sigm(gi) * tanh_(gg);
      float h2 = sigm(go) * tanh_(c);
      if (lane == 0 && s < 254) {  // critical exchange store, immediately
        cstoref(&a.hDec[(s & 1) * 2048 + dir * 1024 + u],
                __uint_as_float((__float_as_uint(h2) & ~3u) | ((unsigned)s & 3u)));
      }
      h2p = h2;
      __syncthreads();  // lockstep: protect smem before next staging
    }
    if (lane == 0) outrec[(size_t)(255 - 254) * 1024 + u] = h2p;  // last row
  }
}

extern "C" void kernel_launch(void* const* d_in, const int* in_sizes, int n_in,
                              void* d_out, int out_size, void* d_ws, size_t ws_size,
                              hipStream_t stream) {
  (void)in_sizes; (void)n_in; (void)out_size;
  KArgs a;
  a.x = (const int*)d_in[0];
  a.Vg = (const int*)d_in[1];
  a.Jg = (const int*)d_in[2];
  a.emb = (const float*)d_in[3];
  a.embVg = (const float*)d_in[4];
  a.embJg = (const float*)d_in[5];
  a.encWih = (const float*)d_in[6];
  a.encWhh = (const float*)d_in[7];
  a.encBih = (const float*)d_in[8];
  a.encBhh = (const float*)d_in[9];
  a.clsW = (const float*)d_in[10];
  a.clsB = (const float*)d_in[11];
  a.latfW = (const float*)d_in[12];
  a.latfB = (const float*)d_in[13];
  a.latrW = (const float*)d_in[14];
  a.latrB = (const float*)d_in[15];
  a.mixW = (const float*)d_in[16];
  a.mixB = (const float*)d_in[17];
  a.recWih[0] = (const float*)d_in[18];
  a.recWhh[0] = (const float*)d_in[19];
  a.recBih[0] = (const float*)d_in[20];
  a.recBhh[0] = (const float*)d_in[21];
  a.recWih[1] = (const float*)d_in[22];
  a.recWhh[1] = (const float*)d_in[23];
  a.recBih[1] = (const float*)d_in[24];
  a.recBhh[1] = (const float*)d_in[25];
  a.out = (float*)d_out;
  char* ws = (char*)d_ws;
  a.barFull = (unsigned*)ws;
  a.eDat = (unsigned long long*)(ws + 4096);
  a.hDec = (float*)(ws + 36864);
  a.common = (float*)(ws + 69632);
  a.bsum = (float*)(ws + 71680);
  a.d1 = (float*)(ws + 104448);
  a.embf = (float*)(ws + 137216);
  a.P = (float*)(ws + 1204224);
  a.Wcomb = (unsigned short*)(ws + 17981440);
  a.WhhE = (unsigned short*)(ws + 34758656);
  a.fast = (ws_size >= 68313088ULL) ? 1 : 0;
  hipMemsetAsync(ws, 0, 4096, stream);  // zero tree-barrier counters only
  hipLaunchKernelGGL(rnn2_kernel, dim3(NB), dim3(NT), 0, stream, a);
}

// Round 7
// 2145.645 us; speedup vs baseline: 1.2584x; 1.2584x over previous
//
#include <hip/hip_runtime.h>
#include <hip/hip_fp16.h>

#define NB 256
#define NT 512

// ---------------- workspace layout (bytes) ----------------
// 0        barrier region (4096)       -- memset 0 each launch (4 tree barriers)
// 4096     eDat  u64[2][2048]  32768   -- packed {hf,hr}, mantissa-LSB 2-bit tag
// 36864    hTdec u64[2][2048]  32768   -- tagged decoder h [buf][dir][1024]
// 69632    common f32[512]      2048
// 71680    bsum  f32[2][4096]  32768
// 104448   d1    f32[2][4096]  32768
// 137216   embf  f32[256][1024] 1048576
// 1204224  P     f32[256][8192] 8388608 -- BLOCK-PRIVATE: 32 rows x 256 t per block
// 17981440 Wcomb fp16[2][4096][1024] 16777216
// 34758656 WhhE  fp16[8192][2048] 33554432
// total fast: 68313088
//
// R13 = R11 verbatim (proven best, 2511us) + ONE algebraic change:
// P[dir1][row][t] == P[dir0][row][255-t]  (reverse emb is just index
// reversal), so the P GEMM is halved (4.3 GFLOP, forward only) AND
// reorganized block-private: block b computes the 32 rows (4 gates x its
// 8 units) x 256 t that its own encoder waves consume, stored with PLAIN
// cached stores/loads (same workgroup -> L1/L2-coherent; no agent scope).
// Encoder: pf[g]=Pp[(g*8+wq)*256+t], pr[g]=Pp[...+255-t] -- bit-identical
// values to R11. Removes 32MB of agent-scope L3 P traffic and takes the
// per-step P loads off the L3 path the polling herd contends on.
// R12's asm-poll/4B-slot/deferred-store deltas all REVERTED (-190us).

struct KArgs {
  const int *x, *Vg, *Jg;
  const float *emb, *embVg, *embJg;
  const float *encWih, *encWhh, *encBih, *encBhh;
  const float *clsW, *clsB, *latfW, *latfB, *latrW, *latrB, *mixW, *mixB;
  const float *recWih[2], *recWhh[2], *recBih[2], *recBhh[2];
  float* out;
  unsigned* barFull;
  unsigned long long *eDat, *hTdec;
  float *common, *bsum, *d1, *embf, *P;
  unsigned short *Wcomb, *WhhE;
  int fast;
};

__device__ __forceinline__ unsigned packh2(float lo, float hi) {
  __half2 h = __floats2half2_rn(lo, hi);
  return *(unsigned*)&h;
}
__device__ __forceinline__ float2 h2f2(unsigned u) {
  __half2 h = *(__half2*)&u;
  return __half22float2(h);
}
__device__ __forceinline__ unsigned long long packtag(unsigned tag, float f) {
  return ((unsigned long long)tag << 32) | (unsigned long long)__float_as_uint(f);
}
__device__ __forceinline__ float sigm(float x) { return 1.f / (1.f + __expf(-x)); }
__device__ __forceinline__ float tanh_(float x) { return 2.f / (1.f + __expf(-2.f * x)) - 1.f; }
__device__ __forceinline__ float wred(float v) {
#pragma unroll
  for (int off = 32; off; off >>= 1) v += __shfl_xor(v, off, 64);
  return v;
}
// agent-scope (device-coherent) accesses: bypass non-coherent per-XCD L2.
__device__ __forceinline__ void cstoref(float* p, float v) {
  __hip_atomic_store(p, v, __ATOMIC_RELAXED, __HIP_MEMORY_SCOPE_AGENT);
}
__device__ __forceinline__ float cloadf(const float* p) {
  return __hip_atomic_load(p, __ATOMIC_RELAXED, __HIP_MEMORY_SCOPE_AGENT);
}
__device__ __forceinline__ void cstoreu(unsigned* p, unsigned v) {
  __hip_atomic_store(p, v, __ATOMIC_RELAXED, __HIP_MEMORY_SCOPE_AGENT);
}
__device__ __forceinline__ unsigned long long cload64(const unsigned long long* p) {
  return __hip_atomic_load(p, __ATOMIC_RELAXED, __HIP_MEMORY_SCOPE_AGENT);
}
__device__ __forceinline__ void cstore64(unsigned long long* p, unsigned long long v) {
  __hip_atomic_store(p, v, __ATOMIC_RELAXED, __HIP_MEMORY_SCOPE_AGENT);
}

// Tree barrier (4 uses). acq-rel RMWs + acquire fence order pre-barrier
// setup stores before post-barrier consumers.
__device__ __forceinline__ void gbar_tree(unsigned* tree, int idx, unsigned e) {
  const int ls = 8;
  __syncthreads();
  if (threadIdx.x == 0) {
    unsigned* leaf = tree + (idx >> 3) * ls;
    unsigned* root = tree + 32 * ls;
    unsigned* flag = root + ls;
    unsigned old = __hip_atomic_fetch_add(leaf, 1u, __ATOMIC_ACQ_REL, __HIP_MEMORY_SCOPE_AGENT);
    if (old == e * 8u - 1u) {
      unsigned ro = __hip_atomic_fetch_add(root, 1u, __ATOMIC_ACQ_REL, __HIP_MEMORY_SCOPE_AGENT);
      if (ro == e * 32u - 1u)
        __hip_atomic_store(flag, e, __ATOMIC_RELEASE, __HIP_MEMORY_SCOPE_AGENT);
    }
    while (__hip_atomic_load(flag, __ATOMIC_RELAXED, __HIP_MEMORY_SCOPE_AGENT) < e)
      __builtin_amdgcn_s_sleep(2);
    __builtin_amdgcn_fence(__ATOMIC_ACQUIRE, "agent");
  }
  __syncthreads();
}

__global__ __launch_bounds__(NT, 2) void rnn2_kernel(KArgs a) {
  __shared__ float smem[16384];  // 64 KB, reused per phase
  const int tid = threadIdx.x;
  const int b = blockIdx.x;
  const int wq = __builtin_amdgcn_readfirstlane(tid >> 6);
  const int lane = tid & 63;

  float* out_recf = a.out + 1280;
  float* out_recr = a.out + 1280 + 262144;
  float* out_embf = a.out + 1280 + 2 * 262144;
  float* out_embr = a.out + 1280 + 3 * 262144;

  // ================= phase 0a =================
  for (int i = tid; i < 2048; i += NT) smem[i] = a.emb[i];
  __syncthreads();
  {  // d1[dir][row] = start_vec @ Wih.T + bih + bhh   (dir0: emb[0], dir1: emb[1])
    int wg = b * 8 + wq;
#pragma unroll 1
    for (int rr = 0; rr < 4; rr++) {
      int idx = wg + rr * 2048;
      int dir = idx >> 12;
      int row = idx & 4095;
      const float* Wih = a.recWih[dir];
      const float* sv = &smem[dir * 1024];
      float acc = 0.f;
#pragma unroll
      for (int kc = 0; kc < 4; kc++) {
        int k = kc * 256 + lane * 4;
        float4 wv = *(const float4*)&Wih[row * 1024 + k];
        float4 ev = *(const float4*)&sv[k];
        acc += wv.x * ev.x + wv.y * ev.y + wv.z * ev.z + wv.w * ev.w;
      }
      acc = wred(acc);
      if (lane == 0)
        cstoref(&a.d1[dir * 4096 + row], acc + a.recBih[dir][row] + a.recBhh[dir][row]);
    }
  }
  const int gtid = b * NT + tid;
  const int GSZ = NB * NT;
  for (int i = gtid; i < 256 * 1024; i += GSZ) {
    int t = i >> 10, e = i & 1023;
    float v = a.emb[a.x[t] * 1024 + e];
    cstoref(&a.embf[i], v);
    out_embf[i] = v;
    out_embr[(255 - t) * 1024 + e] = v;
  }
  if (gtid < 1024) {
    int e = gtid;
    out_recf[e] = a.emb[1024 + e];
    out_recf[255 * 1024 + e] = a.emb[e];
    out_recr[e] = a.emb[e];
    out_recr[255 * 1024 + e] = a.emb[1024 + e];
  }
  // exchange-buffer init (cross-launch-safe):
  // eDat buf0 = 0x0  -> valid tag-0 pattern (0,0) with h0=0 (t=0 poll hits)
  // eDat buf1 = (1,1) pattern -> aliases only t%4==3 polls, overwritten by then
  if (gtid < 2048) cstore64(&a.eDat[gtid], 0ULL);
  else if (gtid < 4096) cstore64(&a.eDat[gtid], 0x0000000100000001ULL);
  if (gtid < 4096) cstore64(&a.hTdec[gtid], packtag(0xFFFFFFFFu, 0.f));
  if (gtid < 8192) {
    int dir = gtid >> 12, r = gtid & 4095;
    cstoref(&a.bsum[gtid], a.recBih[dir][r] + a.recBhh[dir][r]);
  }
  if (a.fast) {
    unsigned* W32 = (unsigned*)a.WhhE;
    const int N4 = 8192 * 2048 / 4;
    for (int i = gtid; i < N4; i += GSZ) {
      float4 v = *(const float4*)&a.encWhh[(size_t)i * 4];
      cstoreu(&W32[i * 2], packh2(v.x, v.y));
      cstoreu(&W32[i * 2 + 1], packh2(v.z, v.w));
    }
    unsigned* C32 = (unsigned*)a.Wcomb;
    const int M4 = 4096 * 1024 / 4;
    for (int i = gtid; i < 2 * M4; i += GSZ) {
      int dir = (i >= M4) ? 1 : 0;
      int j = i - dir * M4;
      float4 va = *(const float4*)&a.recWih[dir][(size_t)j * 4];
      float4 vb = *(const float4*)&a.recWhh[dir][(size_t)j * 4];
      cstoreu(&C32[(size_t)dir * (M4 * 2) + j * 2], packh2(va.x + vb.x, va.y + vb.y));
      cstoreu(&C32[(size_t)dir * (M4 * 2) + j * 2 + 1], packh2(va.z + vb.z, va.w + vb.w));
    }
  }
  gbar_tree(a.barFull, b, 1u);

  // ====== phase 0b: P GEMM, block-private, forward-only (halved) ======
  // Block b computes P0[g][u=b*8+wq][t] for g=0..3, t=0..255 into its
  // private 32KB region. Plain stores; consumer is the same workgroup.
  {
    float* Pp = a.P + (size_t)b * 8192;
    const int s_td = tid >> 3;  // t within 64-chunk
    const int s_j = tid & 7;
#pragma unroll 1
    for (int tc = 0; tc < 4; tc++) {
      float acc[4] = {0.f, 0.f, 0.f, 0.f};
      const float* esrc = &a.embf[(size_t)(tc * 64 + s_td) * 1024];
#pragma unroll 1
      for (int kc = 0; kc < 4; kc++) {
        __syncthreads();
#pragma unroll
        for (int m = 0; m < 8; m++) {
          int kk = s_j * 32 + m * 4;
          float4 v = *(const float4*)&esrc[kc * 256 + kk];
          smem[(kk + 0) * 64 + s_td] = v.x;
          smem[(kk + 1) * 64 + s_td] = v.y;
          smem[(kk + 2) * 64 + s_td] = v.z;
          smem[(kk + 3) * 64 + s_td] = v.w;
        }
        __syncthreads();
#pragma unroll 1
        for (int k4 = 0; k4 < 64; k4++) {
          float e0 = smem[(k4 * 4 + 0) * 64 + lane];
          float e1 = smem[(k4 * 4 + 1) * 64 + lane];
          float e2 = smem[(k4 * 4 + 2) * 64 + lane];
          float e3 = smem[(k4 * 4 + 3) * 64 + lane];
#pragma unroll
          for (int g = 0; g < 4; g++) {
            const float* wp = &a.encWih[(size_t)(g * 2048 + b * 8 + wq) * 1024 + kc * 256 + k4 * 4];
            acc[g] = fmaf(e0, wp[0], fmaf(e1, wp[1], fmaf(e2, wp[2], fmaf(e3, wp[3], acc[g]))));
          }
        }
      }
#pragma unroll
      for (int g = 0; g < 4; g++) {
        int row = g * 2048 + b * 8 + wq;
        Pp[(g * 8 + wq) * 256 + tc * 64 + lane] = acc[g] + a.encBih[row] + a.encBhh[row];
      }
    }
  }
  gbar_tree(a.barFull, b, 2u);

  // ===== encoder: 256 steps, R6 lockstep + packed payload (4 loads) =====
  {
    const int u = b * 8 + wq;
    const float* Pp = a.P + (size_t)b * 8192;  // block-private, cached
    float wreg[128];  // VGPR-resident Whh slice: 4 gates x 2048 k (32 k/lane)
    if (a.fast) {
      const unsigned long long* W64 = (const unsigned long long*)a.WhhE;
#pragma unroll
      for (int g = 0; g < 4; g++)
#pragma unroll
        for (int c = 0; c < 8; c++) {
          unsigned long long w = cload64(&W64[(size_t)(g * 2048 + u) * 512 + c * 64 + lane]);
          float2 f01 = h2f2((unsigned)w), f23 = h2f2((unsigned)(w >> 32));
          wreg[(g * 8 + c) * 4 + 0] = f01.x;
          wreg[(g * 8 + c) * 4 + 1] = f01.y;
          wreg[(g * 8 + c) * 4 + 2] = f23.x;
          wreg[(g * 8 + c) * 4 + 3] = f23.y;
        }
    }
    float cf = 0.f, cr = 0.f;
#pragma unroll 1
    for (int t = 0; t < 256; t++) {
      float pf[4], pr[4];  // plain cached loads (block-private P), issued early
#pragma unroll
      for (int g = 0; g < 4; g++) {
        pf[g] = Pp[(g * 8 + wq) * 256 + t];
        pr[g] = Pp[(g * 8 + wq) * 256 + 255 - t];
      }
      {  // all-or-retry poll: 4 packed u64/thread, batch load + one check
        const unsigned long long* dp = a.eDat + (size_t)(t & 1) * 2048;
        const unsigned lo_e = (unsigned)t & 1u;
        const unsigned hi_e = ((unsigned)t >> 1) & 1u;
        unsigned long long v[4];
        for (;;) {
#pragma unroll
          for (int j = 0; j < 4; j++) v[j] = cload64(&dp[j * 512 + tid]);
          unsigned bad = 0;
#pragma unroll
          for (int j = 0; j < 4; j++)
            bad |= ((unsigned)v[j] ^ lo_e) | (((unsigned)(v[j] >> 32)) ^ hi_e);
          if (!(bad & 1u)) break;
          __builtin_amdgcn_s_sleep(1);
        }
#pragma unroll
        for (int j = 0; j < 4; j++) {
          smem[j * 512 + tid] = __uint_as_float((unsigned)v[j]);
          smem[2048 + j * 512 + tid] = __uint_as_float((unsigned)(v[j] >> 32));
        }
      }
      __syncthreads();
      float af[4] = {0, 0, 0, 0}, ar[4] = {0, 0, 0, 0};
      if (a.fast) {
#pragma unroll
        for (int c = 0; c < 8; c++) {
          float4 hf = *(const float4*)&smem[c * 256 + lane * 4];
          float4 hr = *(const float4*)&smem[2048 + c * 256 + lane * 4];
#pragma unroll
          for (int g = 0; g < 4; g++) {
            const int wb = (g * 8 + c) * 4;
            af[g] = fmaf(wreg[wb + 0], hf.x, fmaf(wreg[wb + 1], hf.y,
                    fmaf(wreg[wb + 2], hf.z, fmaf(wreg[wb + 3], hf.w, af[g]))));
            ar[g] = fmaf(wreg[wb + 0], hr.x, fmaf(wreg[wb + 1], hr.y,
                    fmaf(wreg[wb + 2], hr.z, fmaf(wreg[wb + 3], hr.w, ar[g]))));
          }
        }
      } else {
#pragma unroll 1
        for (int kc = 0; kc < 8; kc++) {
          int k = kc * 256 + lane * 4;
          float4 hf = *(const float4*)&smem[k];
          float4 hr = *(const float4*)&smem[2048 + k];
#pragma unroll
          for (int g = 0; g < 4; g++) {
            float4 wv = *(const float4*)&a.encWhh[(size_t)(g * 2048 + u) * 2048 + k];
            af[g] += wv.x * hf.x + wv.y * hf.y + wv.z * hf.z + wv.w * hf.w;
            ar[g] += wv.x * hr.x + wv.y * hr.y + wv.z * hr.z + wv.w * hr.w;
          }
        }
      }
#pragma unroll
      for (int g = 0; g < 4; g++) { af[g] = wred(af[g]); ar[g] = wred(ar[g]); }
      float gi = af[0] + pf[0], gf = af[1] + pf[1], gg = af[2] + pf[2], go = af[3] + pf[3];
      cf = sigm(gf) * cf + sigm(gi) * tanh_(gg);
      float hfv = sigm(go) * tanh_(cf);
      gi = ar[0] + pr[0]; gf = ar[1] + pr[1]; gg = ar[2] + pr[2]; go = ar[3] + pr[3];
      cr = sigm(gf) * cr + sigm(gi) * tanh_(gg);
      float hrv = sigm(go) * tanh_(cr);
      if (lane == 0) {  // fire-and-forget: packed {hf,hr}, mantissa-LSB tag
        unsigned tag = (unsigned)(t + 1);
        unsigned fa = (__float_as_uint(hfv) & ~1u) | (tag & 1u);
        unsigned fb = (__float_as_uint(hrv) & ~1u) | ((tag >> 1) & 1u);
        cstore64(&a.eDat[(size_t)((t + 1) & 1) * 2048 + u],
                 ((unsigned long long)fb << 32) | fa);
      }
      __syncthreads();  // lockstep: protect smem before next staging
    }
  }

  // ================= latents: tree-barrier sequenced =================
  if (b <= 192) {
    {  // final h: eDat buf 0, tag 256 -> LSB pair (0,0); all-or-retry
      const unsigned long long* dp = a.eDat;
      unsigned long long v[4];
      for (;;) {
#pragma unroll
        for (int j = 0; j < 4; j++) v[j] = cload64(&dp[j * 512 + tid]);
        unsigned bad = 0;
#pragma unroll
        for (int j = 0; j < 4; j++)
          bad |= (unsigned)v[j] | ((unsigned)(v[j] >> 32));
        if (!(bad & 1u)) break;
        __builtin_amdgcn_s_sleep(1);
      }
#pragma unroll
      for (int j = 0; j < 4; j++) {
        smem[j * 512 + tid] = __uint_as_float((unsigned)v[j]);
        smem[2048 + j * 512 + tid] = __uint_as_float((unsigned)(v[j] >> 32));
      }
    }
    __syncthreads();
    int wg = b * 8 + wq;
    if (wg < 512) {  // common row
      int r = wg;
      float acc = 0.f;
#pragma unroll 1
      for (int kc = 0; kc < 16; kc++) {
        int k = kc * 256 + lane * 4;
        float4 wv = *(const float4*)&a.clsW[(size_t)r * 4096 + k];
        float4 hv = *(const float4*)&smem[k];
        acc += wv.x * hv.x + wv.y * hv.y + wv.z * hv.z + wv.w * hv.w;
      }
      acc = wred(acc);
      if (lane == 0) cstoref(&a.common[r], tanh_(acc + a.clsB[r]));
    } else if (wg < 1024) {  // lat_f
      int r = wg - 512;
      float acc = 0.f;
#pragma unroll 1
      for (int kc = 0; kc < 8; kc++) {
        int k = kc * 256 + lane * 4;
        float4 wv = *(const float4*)&a.latfW[(size_t)r * 2048 + k];
        float4 hv = *(const float4*)&smem[k];
        acc += wv.x * hv.x + wv.y * hv.y + wv.z * hv.z + wv.w * hv.w;
      }
      acc = wred(acc);
      if (lane == 0) {
        float v = acc + a.latfB[r];
        cstore64(&a.hTdec[64 + r], packtag(0u, v));
        a.out[64 + r] = v;
      }
    } else if (wg < 1536) {  // lat_r
      int r = wg - 1024;
      float acc = 0.f;
#pragma unroll 1
      for (int kc = 0; kc < 8; kc++) {
        int k = kc * 256 + lane * 4;
        float4 wv = *(const float4*)&a.latrW[(size_t)r * 2048 + k];
        float4 hv = *(const float4*)&smem[2048 + k];
        acc += wv.x * hv.x + wv.y * hv.y + wv.z * hv.z + wv.w * hv.w;
      }
      acc = wred(acc);
      if (lane == 0) {
        float v = acc + a.latrB[r];
        cstore64(&a.hTdec[1024 + 64 + r], packtag(0u, v));
        a.out[640 + 64 + r] = v;
      }
    } else if (wg == 1536) {  // vg
      float v = a.embVg[a.Vg[0] * 64 + lane];
      cstore64(&a.hTdec[lane], packtag(0u, v));
      cstore64(&a.hTdec[1024 + lane], packtag(0u, v));
      a.out[lane] = v;
      a.out[640 + lane] = v;
    } else if (wg == 1537) {  // jg
      float v = a.embJg[a.Jg[0] * 64 + lane];
      cstore64(&a.hTdec[576 + lane], packtag(0u, v));
      cstore64(&a.hTdec[1024 + 576 + lane], packtag(0u, v));
      a.out[576 + lane] = v;
      a.out[640 + 576 + lane] = v;
    }
  }
  gbar_tree(a.barFull, b, 3u);  // common + lat + vg/jg complete, grid-wide
  if (b < 48) {  // mix rows 0..383
    int wg = b * 8 + wq;
    smem[tid] = cloadf(&a.common[tid]);  // 512 threads, 512 entries
    __syncthreads();
    float acc = 0.f;
#pragma unroll
    for (int kc = 0; kc < 2; kc++) {
      int k = kc * 256 + lane * 4;
      float4 wv = *(const float4*)&a.mixW[(size_t)wg * 512 + k];
      float4 hv = *(const float4*)&smem[k];
      acc += wv.x * hv.x + wv.y * hv.y + wv.z * hv.z + wv.w * hv.w;
    }
    acc = wred(acc);
    if (lane == 0) {
      float v = acc + a.mixB[wg];
      cstore64(&a.hTdec[640 + wg], packtag(0u, v));
      cstore64(&a.hTdec[1024 + 640 + wg], packtag(0u, v));
    }
  }
  gbar_tree(a.barFull, b, 4u);  // full h0 (tag 0) in hTdec, grid-wide

  // ========== decoders: 254 steps, R6 tagged exchange (unchanged) ==========
  {
    const int dir = b & 1;
    const int hidx = b >> 1;
    const int u = hidx * 8 + wq;
    float* outrec = dir ? out_recr : out_recf;
    float bs[4];
#pragma unroll
    for (int g = 0; g < 4; g++) bs[g] = cloadf(&a.bsum[dir * 4096 + g * 1024 + u]);
    float wd[64];  // VGPR-resident Wcomb slice: 4 gates x 1024 k (16 k/lane)
    if (a.fast) {
      const unsigned long long* C64 = (const unsigned long long*)a.Wcomb;
      const size_t dbase = (size_t)dir * (4096 * 1024 / 4);
#pragma unroll
      for (int g = 0; g < 4; g++)
#pragma unroll
        for (int c = 0; c < 4; c++) {
          unsigned long long w = cload64(&C64[dbase + (size_t)(g * 1024 + u) * 256 + c * 64 + lane]);
          float2 f01 = h2f2((unsigned)w), f23 = h2f2((unsigned)(w >> 32));
          wd[(g * 4 + c) * 4 + 0] = f01.x;
          wd[(g * 4 + c) * 4 + 1] = f01.y;
          wd[(g * 4 + c) * 4 + 2] = f23.x;
          wd[(g * 4 + c) * 4 + 3] = f23.y;
        }
    }
    float c = 0.f;
#pragma unroll 1
    for (int s = 1; s <= 254; s++) {
      {  // all-or-retry poll: 2 slots/thread, exact 32-bit tag s-1
        const unsigned long long* src = a.hTdec + ((s - 1) & 1) * 2048 + dir * 1024;
        const unsigned tg = (unsigned)(s - 1);
        unsigned long long v0, v1;
        for (;;) {
          v0 = cload64(&src[tid]);
          v1 = cload64(&src[512 + tid]);
          if ((((unsigned)(v0 >> 32)) ^ tg) == 0u && (((unsigned)(v1 >> 32)) ^ tg) == 0u) break;
          __builtin_amdgcn_s_sleep(1);
        }
        smem[tid] = __uint_as_float((unsigned)v0);
        smem[512 + tid] = __uint_as_float((unsigned)v1);
      }
      __syncthreads();
      float acc[4] = {0, 0, 0, 0};
      if (s == 1) {  // g = d1 + h0 @ Whh.T  (f32 weights, one step)
        const float* Whh = a.recWhh[dir];
#pragma unroll 1
        for (int kc = 0; kc < 4; kc++) {
          int k = kc * 256 + lane * 4;
          float4 hv = *(const float4*)&smem[k];
#pragma unroll
          for (int g = 0; g < 4; g++) {
            float4 wv = *(const float4*)&Whh[(size_t)(g * 1024 + u) * 1024 + k];
            acc[g] += wv.x * hv.x + wv.y * hv.y + wv.z * hv.z + wv.w * hv.w;
          }
        }
      } else if (a.fast) {
#pragma unroll
        for (int cc = 0; cc < 4; cc++) {
          float4 hv = *(const float4*)&smem[cc * 256 + lane * 4];
#pragma unroll
          for (int g = 0; g < 4; g++) {
            const int wb = (g * 4 + cc) * 4;
            acc[g] = fmaf(wd[wb + 0], hv.x, fmaf(wd[wb + 1], hv.y,
                     fmaf(wd[wb + 2], hv.z, fmaf(wd[wb + 3], hv.w, acc[g]))));
          }
        }
      } else {
        const float* Wi = a.recWih[dir];
        const float* Wh = a.recWhh[dir];
#pragma unroll 1
        for (int kc = 0; kc < 4; kc++) {
          int k = kc * 256 + lane * 4;
          float4 hv = *(const float4*)&smem[k];
#pragma unroll
          for (int g = 0; g < 4; g++) {
            size_t ro = (size_t)(g * 1024 + u) * 1024 + k;
            float4 va = *(const float4*)&Wi[ro];
            float4 vb = *(const float4*)&Wh[ro];
            acc[g] += (va.x + vb.x) * hv.x + (va.y + vb.y) * hv.y +
                      (va.z + vb.z) * hv.z + (va.w + vb.w) * hv.w;
          }
        }
      }
#pragma unroll
      for (int g = 0; g < 4; g++) acc[g] = wred(acc[g]);
      float gi, gf, gg, go;
      if (s == 1) {
        gi = acc[0] + cloadf(&a.d1[dir * 4096 + u]);
        gf = acc[1] + cloadf(&a.d1[dir * 4096 + 1024 + u]);
        gg = acc[2] + cloadf(&a.d1[dir * 4096 + 2048 + u]);
        go = acc[3] + cloadf(&a.d1[dir * 4096 + 3072 + u]);
        c = smem[u];  // c0 = h0
      } else {
        gi = acc[0] + bs[0]; gf = acc[1] + bs[1]; gg = acc[2] + bs[2]; go = acc[3] + bs[3];
      }
      c = sigm(gf) * c + sigm(gi) * tanh_(gg);
      float h2 = sigm(go) * tanh_(c);
      if (lane == 0) {
        outrec[(size_t)(255 - s) * 1024 + u] = h2;
        if (s < 254)
          cstore64(&a.hTdec[(s & 1) * 2048 + dir * 1024 + u], packtag((unsigned)s, h2));
      }
      __syncthreads();  // lockstep: protect smem before next staging
    }
  }
}

extern "C" void kernel_launch(void* const* d_in, const int* in_sizes, int n_in,
                              void* d_out, int out_size, void* d_ws, size_t ws_size,
                              hipStream_t stream) {
  (void)in_sizes; (void)n_in; (void)out_size;
  KArgs a;
  a.x = (const int*)d_in[0];
  a.Vg = (const int*)d_in[1];
  a.Jg = (const int*)d_in[2];
  a.emb = (const float*)d_in[3];
  a.embVg = (const float*)d_in[4];
  a.embJg = (const float*)d_in[5];
  a.encWih = (const float*)d_in[6];
  a.encWhh = (const float*)d_in[7];
  a.encBih = (const float*)d_in[8];
  a.encBhh = (const float*)d_in[9];
  a.clsW = (const float*)d_in[10];
  a.clsB = (const float*)d_in[11];
  a.latfW = (const float*)d_in[12];
  a.latfB = (const float*)d_in[13];
  a.latrW = (const float*)d_in[14];
  a.latrB = (const float*)d_in[15];
  a.mixW = (const float*)d_in[16];
  a.mixB = (const float*)d_in[17];
  a.recWih[0] = (const float*)d_in[18];
  a.recWhh[0] = (const float*)d_in[19];
  a.recBih[0] = (const float*)d_in[20];
  a.recBhh[0] = (const float*)d_in[21];
  a.recWih[1] = (const float*)d_in[22];
  a.recWhh[1] = (const float*)d_in[23];
  a.recBih[1] = (const float*)d_in[24];
  a.recBhh[1] = (const float*)d_in[25];
  a.out = (float*)d_out;
  char* ws = (char*)d_ws;
  a.barFull = (unsigned*)ws;
  a.eDat = (unsigned long long*)(ws + 4096);
  a.hTdec = (unsigned long long*)(ws + 36864);
  a.common = (float*)(ws + 69632);
  a.bsum = (float*)(ws + 71680);
  a.d1 = (float*)(ws + 104448);
  a.embf = (float*)(ws + 137216);
  a.P = (float*)(ws + 1204224);
  a.Wcomb = (unsigned short*)(ws + 17981440);
  a.WhhE = (unsigned short*)(ws + 34758656);
  a.fast = (ws_size >= 68313088ULL) ? 1 : 0;
  hipMemsetAsync(ws, 0, 4096, stream);  // zero tree-barrier counters only
  hipLaunchKernelGGL(rnn2_kernel, dim3(NB), dim3(NT), 0, stream, a);
}

// Round 8
// 2009.567 us; speedup vs baseline: 1.3437x; 1.0677x over previous
//
#include <hip/hip_runtime.h>
#include <hip/hip_fp16.h>

#define NB 256
#define NT 512

// ---------------- workspace layout (bytes) ----------------
// 0        barrier region (4096)       -- memset 0 each launch (4 tree barriers)
// 4096     eDat  u64[2][2048]  32768   -- packed {hf,hr}, mantissa-LSB 2-bit tag
// 36864    hTdec u64[2][2048]  32768   -- tagged decoder h [buf][dir][1024]
// 69632    common f32[512]      2048
// 71680    bsum  f32[2][4096]  32768
// 104448   d1    f32[2][4096]  32768
// 137216   embf  f32[256][1024] 1048576
// 1204224  P     f32[256][8192] 8388608 -- BLOCK-PRIVATE: 32 rows x 256 t per block
// (9592832 total used; fp16 repack regions DELETED in R14)
//
// R14 = R13 (2145us, proven) + delete the weight repack fossil:
// wreg/wd are loaded into VGPRs ONCE before the step loops, so the fp16
// repack (128MB HBM reads + 48MB agent stores + 48MB readback + pack VALU)
// only accelerated a one-time 64MB load to 32MB -- strictly negative now.
// Encoder loads encWhh f32 directly (same k->lane map, float4 coalesced);
// decoder loads recWih+recWhh f32 and sums in registers. Numerics move
// TOWARD reference (f32 weights): absmax <= 0.01025.
// R13 recap: block-private forward-only P (P[dir1][row][t]==P[dir0][row][255-t]),
// plain cached P loads; R11 exchange: lockstep 2-barrier, all-or-retry poll,
// packed {hf,hr} eDat with mantissa-LSB mod-4 tags, fire-and-forget stores.

struct KArgs {
  const int *x, *Vg, *Jg;
  const float *emb, *embVg, *embJg;
  const float *encWih, *encWhh, *encBih, *encBhh;
  const float *clsW, *clsB, *latfW, *latfB, *latrW, *latrB, *mixW, *mixB;
  const float *recWih[2], *recWhh[2], *recBih[2], *recBhh[2];
  float* out;
  unsigned* barFull;
  unsigned long long *eDat, *hTdec;
  float *common, *bsum, *d1, *embf, *P;
  int fast;
};

__device__ __forceinline__ unsigned long long packtag(unsigned tag, float f) {
  return ((unsigned long long)tag << 32) | (unsigned long long)__float_as_uint(f);
}
__device__ __forceinline__ float sigm(float x) { return 1.f / (1.f + __expf(-x)); }
__device__ __forceinline__ float tanh_(float x) { return 2.f / (1.f + __expf(-2.f * x)) - 1.f; }
__device__ __forceinline__ float wred(float v) {
#pragma unroll
  for (int off = 32; off; off >>= 1) v += __shfl_xor(v, off, 64);
  return v;
}
// agent-scope (device-coherent) accesses: bypass non-coherent per-XCD L2.
__device__ __forceinline__ void cstoref(float* p, float v) {
  __hip_atomic_store(p, v, __ATOMIC_RELAXED, __HIP_MEMORY_SCOPE_AGENT);
}
__device__ __forceinline__ float cloadf(const float* p) {
  return __hip_atomic_load(p, __ATOMIC_RELAXED, __HIP_MEMORY_SCOPE_AGENT);
}
__device__ __forceinline__ unsigned long long cload64(const unsigned long long* p) {
  return __hip_atomic_load(p, __ATOMIC_RELAXED, __HIP_MEMORY_SCOPE_AGENT);
}
__device__ __forceinline__ void cstore64(unsigned long long* p, unsigned long long v) {
  __hip_atomic_store(p, v, __ATOMIC_RELAXED, __HIP_MEMORY_SCOPE_AGENT);
}

// Tree barrier (4 uses). acq-rel RMWs + acquire fence order pre-barrier
// setup stores before post-barrier consumers.
__device__ __forceinline__ void gbar_tree(unsigned* tree, int idx, unsigned e) {
  const int ls = 8;
  __syncthreads();
  if (threadIdx.x == 0) {
    unsigned* leaf = tree + (idx >> 3) * ls;
    unsigned* root = tree + 32 * ls;
    unsigned* flag = root + ls;
    unsigned old = __hip_atomic_fetch_add(leaf, 1u, __ATOMIC_ACQ_REL, __HIP_MEMORY_SCOPE_AGENT);
    if (old == e * 8u - 1u) {
      unsigned ro = __hip_atomic_fetch_add(root, 1u, __ATOMIC_ACQ_REL, __HIP_MEMORY_SCOPE_AGENT);
      if (ro == e * 32u - 1u)
        __hip_atomic_store(flag, e, __ATOMIC_RELEASE, __HIP_MEMORY_SCOPE_AGENT);
    }
    while (__hip_atomic_load(flag, __ATOMIC_RELAXED, __HIP_MEMORY_SCOPE_AGENT) < e)
      __builtin_amdgcn_s_sleep(2);
    __builtin_amdgcn_fence(__ATOMIC_ACQUIRE, "agent");
  }
  __syncthreads();
}

__global__ __launch_bounds__(NT, 2) void rnn2_kernel(KArgs a) {
  __shared__ float smem[16384];  // 64 KB, reused per phase
  const int tid = threadIdx.x;
  const int b = blockIdx.x;
  const int wq = __builtin_amdgcn_readfirstlane(tid >> 6);
  const int lane = tid & 63;

  float* out_recf = a.out + 1280;
  float* out_recr = a.out + 1280 + 262144;
  float* out_embf = a.out + 1280 + 2 * 262144;
  float* out_embr = a.out + 1280 + 3 * 262144;

  // ================= phase 0a =================
  for (int i = tid; i < 2048; i += NT) smem[i] = a.emb[i];
  __syncthreads();
  {  // d1[dir][row] = start_vec @ Wih.T + bih + bhh   (dir0: emb[0], dir1: emb[1])
    int wg = b * 8 + wq;
#pragma unroll 1
    for (int rr = 0; rr < 4; rr++) {
      int idx = wg + rr * 2048;
      int dir = idx >> 12;
      int row = idx & 4095;
      const float* Wih = a.recWih[dir];
      const float* sv = &smem[dir * 1024];
      float acc = 0.f;
#pragma unroll
      for (int kc = 0; kc < 4; kc++) {
        int k = kc * 256 + lane * 4;
        float4 wv = *(const float4*)&Wih[row * 1024 + k];
        float4 ev = *(const float4*)&sv[k];
        acc += wv.x * ev.x + wv.y * ev.y + wv.z * ev.z + wv.w * ev.w;
      }
      acc = wred(acc);
      if (lane == 0)
        cstoref(&a.d1[dir * 4096 + row], acc + a.recBih[dir][row] + a.recBhh[dir][row]);
    }
  }
  const int gtid = b * NT + tid;
  const int GSZ = NB * NT;
  for (int i = gtid; i < 256 * 1024; i += GSZ) {
    int t = i >> 10, e = i & 1023;
    float v = a.emb[a.x[t] * 1024 + e];
    cstoref(&a.embf[i], v);
    out_embf[i] = v;
    out_embr[(255 - t) * 1024 + e] = v;
  }
  if (gtid < 1024) {
    int e = gtid;
    out_recf[e] = a.emb[1024 + e];
    out_recf[255 * 1024 + e] = a.emb[e];
    out_recr[e] = a.emb[e];
    out_recr[255 * 1024 + e] = a.emb[1024 + e];
  }
  // exchange-buffer init (cross-launch-safe):
  // eDat buf0 = 0x0  -> valid tag-0 pattern (0,0) with h0=0 (t=0 poll hits)
  // eDat buf1 = (1,1) pattern -> aliases only t%4==3 polls, overwritten by then
  if (gtid < 2048) cstore64(&a.eDat[gtid], 0ULL);
  else if (gtid < 4096) cstore64(&a.eDat[gtid], 0x0000000100000001ULL);
  if (gtid < 4096) cstore64(&a.hTdec[gtid], packtag(0xFFFFFFFFu, 0.f));
  if (gtid < 8192) {
    int dir = gtid >> 12, r = gtid & 4095;
    cstoref(&a.bsum[gtid], a.recBih[dir][r] + a.recBhh[dir][r]);
  }
  gbar_tree(a.barFull, b, 1u);

  // ====== phase 0b: P GEMM, block-private, forward-only (halved) ======
  // Block b computes P0[g][u=b*8+wq][t] for g=0..3, t=0..255 into its
  // private 32KB region. Plain stores; consumer is the same workgroup.
  {
    float* Pp = a.P + (size_t)b * 8192;
    const int s_td = tid >> 3;  // t within 64-chunk
    const int s_j = tid & 7;
#pragma unroll 1
    for (int tc = 0; tc < 4; tc++) {
      float acc[4] = {0.f, 0.f, 0.f, 0.f};
      const float* esrc = &a.embf[(size_t)(tc * 64 + s_td) * 1024];
#pragma unroll 1
      for (int kc = 0; kc < 4; kc++) {
        __syncthreads();
#pragma unroll
        for (int m = 0; m < 8; m++) {
          int kk = s_j * 32 + m * 4;
          float4 v = *(const float4*)&esrc[kc * 256 + kk];
          smem[(kk + 0) * 64 + s_td] = v.x;
          smem[(kk + 1) * 64 + s_td] = v.y;
          smem[(kk + 2) * 64 + s_td] = v.z;
          smem[(kk + 3) * 64 + s_td] = v.w;
        }
        __syncthreads();
#pragma unroll 1
        for (int k4 = 0; k4 < 64; k4++) {
          float e0 = smem[(k4 * 4 + 0) * 64 + lane];
          float e1 = smem[(k4 * 4 + 1) * 64 + lane];
          float e2 = smem[(k4 * 4 + 2) * 64 + lane];
          float e3 = smem[(k4 * 4 + 3) * 64 + lane];
#pragma unroll
          for (int g = 0; g < 4; g++) {
            const float* wp = &a.encWih[(size_t)(g * 2048 + b * 8 + wq) * 1024 + kc * 256 + k4 * 4];
            acc[g] = fmaf(e0, wp[0], fmaf(e1, wp[1], fmaf(e2, wp[2], fmaf(e3, wp[3], acc[g]))));
          }
        }
      }
#pragma unroll
      for (int g = 0; g < 4; g++) {
        int row = g * 2048 + b * 8 + wq;
        Pp[(g * 8 + wq) * 256 + tc * 64 + lane] = acc[g] + a.encBih[row] + a.encBhh[row];
      }
    }
  }
  gbar_tree(a.barFull, b, 2u);

  // ===== encoder: 256 steps, lockstep + packed payload (4 loads) =====
  {
    const int u = b * 8 + wq;
    const float* Pp = a.P + (size_t)b * 8192;  // block-private, cached
    float wreg[128];  // VGPR-resident Whh slice: 4 gates x 2048 k (32 k/lane)
    if (a.fast) {     // direct f32 load, one-time, coalesced float4
#pragma unroll
      for (int g = 0; g < 4; g++)
#pragma unroll
        for (int c = 0; c < 8; c++) {
          float4 wv = *(const float4*)&a.encWhh[(size_t)(g * 2048 + u) * 2048 + c * 256 + lane * 4];
          wreg[(g * 8 + c) * 4 + 0] = wv.x;
          wreg[(g * 8 + c) * 4 + 1] = wv.y;
          wreg[(g * 8 + c) * 4 + 2] = wv.z;
          wreg[(g * 8 + c) * 4 + 3] = wv.w;
        }
    }
    float cf = 0.f, cr = 0.f;
#pragma unroll 1
    for (int t = 0; t < 256; t++) {
      float pf[4], pr[4];  // plain cached loads (block-private P), issued early
#pragma unroll
      for (int g = 0; g < 4; g++) {
        pf[g] = Pp[(g * 8 + wq) * 256 + t];
        pr[g] = Pp[(g * 8 + wq) * 256 + 255 - t];
      }
      {  // all-or-retry poll: 4 packed u64/thread, batch load + one check
        const unsigned long long* dp = a.eDat + (size_t)(t & 1) * 2048;
        const unsigned lo_e = (unsigned)t & 1u;
        const unsigned hi_e = ((unsigned)t >> 1) & 1u;
        unsigned long long v[4];
        for (;;) {
#pragma unroll
          for (int j = 0; j < 4; j++) v[j] = cload64(&dp[j * 512 + tid]);
          unsigned bad = 0;
#pragma unroll
          for (int j = 0; j < 4; j++)
            bad |= ((unsigned)v[j] ^ lo_e) | (((unsigned)(v[j] >> 32)) ^ hi_e);
          if (!(bad & 1u)) break;
          __builtin_amdgcn_s_sleep(1);
        }
#pragma unroll
        for (int j = 0; j < 4; j++) {
          smem[j * 512 + tid] = __uint_as_float((unsigned)v[j]);
          smem[2048 + j * 512 + tid] = __uint_as_float((unsigned)(v[j] >> 32));
        }
      }
      __syncthreads();
      float af[4] = {0, 0, 0, 0}, ar[4] = {0, 0, 0, 0};
      if (a.fast) {
#pragma unroll
        for (int c = 0; c < 8; c++) {
          float4 hf = *(const float4*)&smem[c * 256 + lane * 4];
          float4 hr = *(const float4*)&smem[2048 + c * 256 + lane * 4];
#pragma unroll
          for (int g = 0; g < 4; g++) {
            const int wb = (g * 8 + c) * 4;
            af[g] = fmaf(wreg[wb + 0], hf.x, fmaf(wreg[wb + 1], hf.y,
                    fmaf(wreg[wb + 2], hf.z, fmaf(wreg[wb + 3], hf.w, af[g]))));
            ar[g] = fmaf(wreg[wb + 0], hr.x, fmaf(wreg[wb + 1], hr.y,
                    fmaf(wreg[wb + 2], hr.z, fmaf(wreg[wb + 3], hr.w, ar[g]))));
          }
        }
      } else {
#pragma unroll 1
        for (int kc = 0; kc < 8; kc++) {
          int k = kc * 256 + lane * 4;
          float4 hf = *(const float4*)&smem[k];
          float4 hr = *(const float4*)&smem[2048 + k];
#pragma unroll
          for (int g = 0; g < 4; g++) {
            float4 wv = *(const float4*)&a.encWhh[(size_t)(g * 2048 + u) * 2048 + k];
            af[g] += wv.x * hf.x + wv.y * hf.y + wv.z * hf.z + wv.w * hf.w;
            ar[g] += wv.x * hr.x + wv.y * hr.y + wv.z * hr.z + wv.w * hr.w;
          }
        }
      }
#pragma unroll
      for (int g = 0; g < 4; g++) { af[g] = wred(af[g]); ar[g] = wred(ar[g]); }
      float gi = af[0] + pf[0], gf = af[1] + pf[1], gg = af[2] + pf[2], go = af[3] + pf[3];
      cf = sigm(gf) * cf + sigm(gi) * tanh_(gg);
      float hfv = sigm(go) * tanh_(cf);
      gi = ar[0] + pr[0]; gf = ar[1] + pr[1]; gg = ar[2] + pr[2]; go = ar[3] + pr[3];
      cr = sigm(gf) * cr + sigm(gi) * tanh_(gg);
      float hrv = sigm(go) * tanh_(cr);
      if (lane == 0) {  // fire-and-forget: packed {hf,hr}, mantissa-LSB tag
        unsigned tag = (unsigned)(t + 1);
        unsigned fa = (__float_as_uint(hfv) & ~1u) | (tag & 1u);
        unsigned fb = (__float_as_uint(hrv) & ~1u) | ((tag >> 1) & 1u);
        cstore64(&a.eDat[(size_t)((t + 1) & 1) * 2048 + u],
                 ((unsigned long long)fb << 32) | fa);
      }
      __syncthreads();  // lockstep: protect smem before next staging
    }
  }

  // ================= latents: tree-barrier sequenced =================
  if (b <= 192) {
    {  // final h: eDat buf 0, tag 256 -> LSB pair (0,0); all-or-retry
      const unsigned long long* dp = a.eDat;
      unsigned long long v[4];
      for (;;) {
#pragma unroll
        for (int j = 0; j < 4; j++) v[j] = cload64(&dp[j * 512 + tid]);
        unsigned bad = 0;
#pragma unroll
        for (int j = 0; j < 4; j++)
          bad |= (unsigned)v[j] | ((unsigned)(v[j] >> 32));
        if (!(bad & 1u)) break;
        __builtin_amdgcn_s_sleep(1);
      }
#pragma unroll
      for (int j = 0; j < 4; j++) {
        smem[j * 512 + tid] = __uint_as_float((unsigned)v[j]);
        smem[2048 + j * 512 + tid] = __uint_as_float((unsigned)(v[j] >> 32));
      }
    }
    __syncthreads();
    int wg = b * 8 + wq;
    if (wg < 512) {  // common row
      int r = wg;
      float acc = 0.f;
#pragma unroll 1
      for (int kc = 0; kc < 16; kc++) {
        int k = kc * 256 + lane * 4;
        float4 wv = *(const float4*)&a.clsW[(size_t)r * 4096 + k];
        float4 hv = *(const float4*)&smem[k];
        acc += wv.x * hv.x + wv.y * hv.y + wv.z * hv.z + wv.w * hv.w;
      }
      acc = wred(acc);
      if (lane == 0) cstoref(&a.common[r], tanh_(acc + a.clsB[r]));
    } else if (wg < 1024) {  // lat_f
      int r = wg - 512;
      float acc = 0.f;
#pragma unroll 1
      for (int kc = 0; kc < 8; kc++) {
        int k = kc * 256 + lane * 4;
        float4 wv = *(const float4*)&a.latfW[(size_t)r * 2048 + k];
        float4 hv = *(const float4*)&smem[k];
        acc += wv.x * hv.x + wv.y * hv.y + wv.z * hv.z + wv.w * hv.w;
      }
      acc = wred(acc);
      if (lane == 0) {
        float v = acc + a.latfB[r];
        cstore64(&a.hTdec[64 + r], packtag(0u, v));
        a.out[64 + r] = v;
      }
    } else if (wg < 1536) {  // lat_r
      int r = wg - 1024;
      float acc = 0.f;
#pragma unroll 1
      for (int kc = 0; kc < 8; kc++) {
        int k = kc * 256 + lane * 4;
        float4 wv = *(const float4*)&a.latrW[(size_t)r * 2048 + k];
        float4 hv = *(const float4*)&smem[2048 + k];
        acc += wv.x * hv.x + wv.y * hv.y + wv.z * hv.z + wv.w * hv.w;
      }
      acc = wred(acc);
      if (lane == 0) {
        float v = acc + a.latrB[r];
        cstore64(&a.hTdec[1024 + 64 + r], packtag(0u, v));
        a.out[640 + 64 + r] = v;
      }
    } else if (wg == 1536) {  // vg
      float v = a.embVg[a.Vg[0] * 64 + lane];
      cstore64(&a.hTdec[lane], packtag(0u, v));
      cstore64(&a.hTdec[1024 + lane], packtag(0u, v));
      a.out[lane] = v;
      a.out[640 + lane] = v;
    } else if (wg == 1537) {  // jg
      float v = a.embJg[a.Jg[0] * 64 + lane];
      cstore64(&a.hTdec[576 + lane], packtag(0u, v));
      cstore64(&a.hTdec[1024 + 576 + lane], packtag(0u, v));
      a.out[576 + lane] = v;
      a.out[640 + 576 + lane] = v;
    }
  }
  gbar_tree(a.barFull, b, 3u);  // common + lat + vg/jg complete, grid-wide
  if (b < 48) {  // mix rows 0..383
    int wg = b * 8 + wq;
    smem[tid] = cloadf(&a.common[tid]);  // 512 threads, 512 entries
    __syncthreads();
    float acc = 0.f;
#pragma unroll
    for (int kc = 0; kc < 2; kc++) {
      int k = kc * 256 + lane * 4;
      float4 wv = *(const float4*)&a.mixW[(size_t)wg * 512 + k];
      float4 hv = *(const float4*)&smem[k];
      acc += wv.x * hv.x + wv.y * hv.y + wv.z * hv.z + wv.w * hv.w;
    }
    acc = wred(acc);
    if (lane == 0) {
      float v = acc + a.mixB[wg];
      cstore64(&a.hTdec[640 + wg], packtag(0u, v));
      cstore64(&a.hTdec[1024 + 640 + wg], packtag(0u, v));
    }
  }
  gbar_tree(a.barFull, b, 4u);  // full h0 (tag 0) in hTdec, grid-wide

  // ========== decoders: 254 steps, tagged exchange ==========
  {
    const int dir = b & 1;
    const int hidx = b >> 1;
    const int u = hidx * 8 + wq;
    float* outrec = dir ? out_recr : out_recf;
    float bs[4];
#pragma unroll
    for (int g = 0; g < 4; g++) bs[g] = cloadf(&a.bsum[dir * 4096 + g * 1024 + u]);
    float wd[64];  // VGPR-resident (Wih+Whh) slice: 4 gates x 1024 k (16 k/lane)
    if (a.fast) {  // direct f32 loads + register sum, one-time
      const float* Wi = a.recWih[dir];
      const float* Wh = a.recWhh[dir];
#pragma unroll
      for (int g = 0; g < 4; g++)
#pragma unroll
        for (int c = 0; c < 4; c++) {
          size_t ro = (size_t)(g * 1024 + u) * 1024 + c * 256 + lane * 4;
          float4 va = *(const float4*)&Wi[ro];
          float4 vb = *(const float4*)&Wh[ro];
          wd[(g * 4 + c) * 4 + 0] = va.x + vb.x;
          wd[(g * 4 + c) * 4 + 1] = va.y + vb.y;
          wd[(g * 4 + c) * 4 + 2] = va.z + vb.z;
          wd[(g * 4 + c) * 4 + 3] = va.w + vb.w;
        }
    }
    float c = 0.f;
#pragma unroll 1
    for (int s = 1; s <= 254; s++) {
      {  // all-or-retry poll: 2 slots/thread, exact 32-bit tag s-1
        const unsigned long long* src = a.hTdec + ((s - 1) & 1) * 2048 + dir * 1024;
        const unsigned tg = (unsigned)(s - 1);
        unsigned long long v0, v1;
        for (;;) {
          v0 = cload64(&src[tid]);
          v1 = cload64(&src[512 + tid]);
          if ((((unsigned)(v0 >> 32)) ^ tg) == 0u && (((unsigned)(v1 >> 32)) ^ tg) == 0u) break;
          __builtin_amdgcn_s_sleep(1);
        }
        smem[tid] = __uint_as_float((unsigned)v0);
        smem[512 + tid] = __uint_as_float((unsigned)v1);
      }
      __syncthreads();
      float acc[4] = {0, 0, 0, 0};
      if (s == 1) {  // g = d1 + h0 @ Whh.T  (f32 weights, one step)
        const float* Whh = a.recWhh[dir];
#pragma unroll 1
        for (int kc = 0; kc < 4; kc++) {
          int k = kc * 256 + lane * 4;
          float4 hv = *(const float4*)&smem[k];
#pragma unroll
          for (int g = 0; g < 4; g++) {
            float4 wv = *(const float4*)&Whh[(size_t)(g * 1024 + u) * 1024 + k];
            acc[g] += wv.x * hv.x + wv.y * hv.y + wv.z * hv.z + wv.w * hv.w;
          }
        }
      } else if (a.fast) {
#pragma unroll
        for (int cc = 0; cc < 4; cc++) {
          float4 hv = *(const float4*)&smem[cc * 256 + lane * 4];
#pragma unroll
          for (int g = 0; g < 4; g++) {
            const int wb = (g * 4 + cc) * 4;
            acc[g] = fmaf(wd[wb + 0], hv.x, fmaf(wd[wb + 1], hv.y,
                     fmaf(wd[wb + 2], hv.z, fmaf(wd[wb + 3], hv.w, acc[g]))));
          }
        }
      } else {
        const float* Wi = a.recWih[dir];
        const float* Wh = a.recWhh[dir];
#pragma unroll 1
        for (int kc = 0; kc < 4; kc++) {
          int k = kc * 256 + lane * 4;
          float4 hv = *(const float4*)&smem[k];
#pragma unroll
          for (int g = 0; g < 4; g++) {
            size_t ro = (size_t)(g * 1024 + u) * 1024 + k;
            float4 va = *(const float4*)&Wi[ro];
            float4 vb = *(const float4*)&Wh[ro];
            acc[g] += (va.x + vb.x) * hv.x + (va.y + vb.y) * hv.y +
                      (va.z + vb.z) * hv.z + (va.w + vb.w) * hv.w;
          }
        }
      }
#pragma unroll
      for (int g = 0; g < 4; g++) acc[g] = wred(acc[g]);
      float gi, gf, gg, go;
      if (s == 1) {
        gi = acc[0] + cloadf(&a.d1[dir * 4096 + u]);
        gf = acc[1] + cloadf(&a.d1[dir * 4096 + 1024 + u]);
        gg = acc[2] + cloadf(&a.d1[dir * 4096 + 2048 + u]);
        go = acc[3] + cloadf(&a.d1[dir * 4096 + 3072 + u]);
        c = smem[u];  // c0 = h0
      } else {
        gi = acc[0] + bs[0]; gf = acc[1] + bs[1]; gg = acc[2] + bs[2]; go = acc[3] + bs[3];
      }
      c = sigm(gf) * c + sigm(gi) * tanh_(gg);
      float h2 = sigm(go) * tanh_(c);
      if (lane == 0) {
        outrec[(size_t)(255 - s) * 1024 + u] = h2;
        if (s < 254)
          cstore64(&a.hTdec[(s & 1) * 2048 + dir * 1024 + u], packtag((unsigned)s, h2));
      }
      __syncthreads();  // lockstep: protect smem before next staging
    }
  }
}

extern "C" void kernel_launch(void* const* d_in, const int* in_sizes, int n_in,
                              void* d_out, int out_size, void* d_ws, size_t ws_size,
                              hipStream_t stream) {
  (void)in_sizes; (void)n_in; (void)out_size;
  KArgs a;
  a.x = (const int*)d_in[0];
  a.Vg = (const int*)d_in[1];
  a.Jg = (const int*)d_in[2];
  a.emb = (const float*)d_in[3];
  a.embVg = (const float*)d_in[4];
  a.embJg = (const float*)d_in[5];
  a.encWih = (const float*)d_in[6];
  a.encWhh = (const float*)d_in[7];
  a.encBih = (const float*)d_in[8];
  a.encBhh = (const float*)d_in[9];
  a.clsW = (const float*)d_in[10];
  a.clsB = (const float*)d_in[11];
  a.latfW = (const float*)d_in[12];
  a.latfB = (const float*)d_in[13];
  a.latrW = (const float*)d_in[14];
  a.latrB = (const float*)d_in[15];
  a.mixW = (const float*)d_in[16];
  a.mixB = (const float*)d_in[17];
  a.recWih[0] = (const float*)d_in[18];
  a.recWhh[0] = (const float*)d_in[19];
  a.recBih[0] = (const float*)d_in[20];
  a.recBhh[0] = (const float*)d_in[21];
  a.recWih[1] = (const float*)d_in[22];
  a.recWhh[1] = (const float*)d_in[23];
  a.recBih[1] = (const float*)d_in[24];
  a.recBhh[1] = (const float*)d_in[25];
  a.out = (float*)d_out;
  char* ws = (char*)d_ws;
  a.barFull = (unsigned*)ws;
  a.eDat = (unsigned long long*)(ws + 4096);
  a.hTdec = (unsigned long long*)(ws + 36864);
  a.common = (float*)(ws + 69632);
  a.bsum = (float*)(ws + 71680);
  a.d1 = (float*)(ws + 104448);
  a.embf = (float*)(ws + 137216);
  a.P = (float*)(ws + 1204224);
  a.fast = (ws_size >= 9592832ULL) ? 1 : 0;
  hipMemsetAsync(ws, 0, 4096, stream);  // zero tree-barrier counters only
  hipLaunchKernelGGL(rnn2_kernel, dim3(NB), dim3(NT), 0, stream, a);
}